// Round 7
// baseline (451.686 us; speedup 1.0000x reference)
//
#include <hip/hip_runtime.h>
#include <hip/hip_bf16.h>
#include <type_traits>

#define BATCH 2
#define SEQ   8192
#define CH    1024
#define NH    16
#define BLK   64
#define WIN   192
#define NBL   128
#define DH    64
#define MR    (BATCH*SEQ)   // 16384

typedef __bf16 bf16x8 __attribute__((ext_vector_type(8)));
typedef float  f32x4  __attribute__((ext_vector_type(4)));

__device__ __forceinline__ f32x4 zero4() {
    f32x4 z; z[0]=0.f; z[1]=0.f; z[2]=0.f; z[3]=0.f; return z;
}

union Pack8 { __hip_bfloat16 h[8]; uint4 u; };

typedef const __attribute__((address_space(1))) unsigned int* gas_ptr;
typedef       __attribute__((address_space(3))) unsigned int* las_ptr;

__device__ __forceinline__ void gload_lds16(const __hip_bfloat16* g, __hip_bfloat16* l) {
    __builtin_amdgcn_global_load_lds((gas_ptr)(const void*)g, (las_ptr)(void*)l, 16, 0, 0);
}

__device__ __forceinline__ int xcd_swz(int bid, int nwg) {
    return (bid & 7) * (nwg >> 3) + (bid >> 3);
}

// ---- weights-only fp32 -> bf16 pack (activations now converted in-GEMM)
__global__ __launch_bounds__(256) void pack_w(
    const float* __restrict__ wq, const float* __restrict__ wk,
    const float* __restrict__ wv, const float* __restrict__ wo,
    __hip_bfloat16* __restrict__ wqb, __hip_bfloat16* __restrict__ wkb,
    __hip_bfloat16* __restrict__ wvb, __hip_bfloat16* __restrict__ wob)
{
    const int NW8B = (CH * CH / 8) / 256;   // 512 blocks per weight
    int bid = blockIdx.x;
    int t = bid >> 9, rel = bid & (NW8B - 1);
    const float* src = (t == 0) ? wq : (t == 1) ? wk : (t == 2) ? wv : wo;
    __hip_bfloat16* dst = (t == 0) ? wqb : (t == 1) ? wkb : (t == 2) ? wvb : wob;
    const int base = rel * 512;             // float4 units
    const float4* s = reinterpret_cast<const float4*>(src);
    uint2* d = reinterpret_cast<uint2*>(dst);
    float4 a = s[base + threadIdx.x];
    float4 b = s[base + 256 + threadIdx.x];
    union { __hip_bfloat16 h[4]; uint2 u; } pa, pb;
    pa.h[0] = __float2bfloat16(a.x); pa.h[1] = __float2bfloat16(a.y);
    pa.h[2] = __float2bfloat16(a.z); pa.h[3] = __float2bfloat16(a.w);
    pb.h[0] = __float2bfloat16(b.x); pb.h[1] = __float2bfloat16(b.y);
    pb.h[2] = __float2bfloat16(b.z); pb.h[3] = __float2bfloat16(b.w);
    d[base + threadIdx.x]       = pa.u;
    d[base + 256 + threadIdx.x] = pb.u;
}

// =====================================================================
// 256x256 GEMM, BK=64, 8 waves (2M x 4N), 4-phase-per-tile schedule.
// AT=float: A read fp32 from global, converted in-register, ds_write'd
// into the swizzled LDS layout (fuses the old pack_bf16).  Ledger:
//   p0 issues [A-klo x4 fp32 loads][B-klo x2 gl_lds] for tile t+1
//   p2 issues [A-khi x4][B-khi x2]
//   p1 start: vmcnt(2) -> {B-khi(t), A-klo(t+1)} done -> write klo
//   p3 start: vmcnt(2) -> {B-klo(t+1), A-khi(t+1)} done -> write khi
// (8 in flight steady-state; never drained to 0 in the main loop.)
// AT=bf16: exact R4 schedule (stages p0/p1/p2/p3, VMCNT(4) at p1/p3 end).
// =====================================================================

__device__ __forceinline__ void stage_half(
    const __hip_bfloat16* __restrict__ g, int goff,
    __hip_bfloat16* sm, int loff, int tid)
{
    gload_lds16(g + goff,            sm + loff + tid * 8);
    gload_lds16(g + goff + 128 * CH, sm + loff + (tid + 512) * 8);
}

__device__ __forceinline__ void stageA32_load(
    const float* __restrict__ g, int goff, float4 (&fr)[4])
{
    const float4* p0 = reinterpret_cast<const float4*>(g + goff);
    const float4* p1 = reinterpret_cast<const float4*>(g + goff + 128 * CH);
    fr[0] = p0[0]; fr[1] = p0[1];
    fr[2] = p1[0]; fr[3] = p1[1];
}

__device__ __forceinline__ void stageA32_write(
    const float4 (&fr)[4], __hip_bfloat16* sm, int loff, int tid)
{
    Pack8 pa, pb;
    pa.h[0] = __float2bfloat16(fr[0].x); pa.h[1] = __float2bfloat16(fr[0].y);
    pa.h[2] = __float2bfloat16(fr[0].z); pa.h[3] = __float2bfloat16(fr[0].w);
    pa.h[4] = __float2bfloat16(fr[1].x); pa.h[5] = __float2bfloat16(fr[1].y);
    pa.h[6] = __float2bfloat16(fr[1].z); pa.h[7] = __float2bfloat16(fr[1].w);
    pb.h[0] = __float2bfloat16(fr[2].x); pb.h[1] = __float2bfloat16(fr[2].y);
    pb.h[2] = __float2bfloat16(fr[2].z); pb.h[3] = __float2bfloat16(fr[2].w);
    pb.h[4] = __float2bfloat16(fr[3].x); pb.h[5] = __float2bfloat16(fr[3].y);
    pb.h[6] = __float2bfloat16(fr[3].z); pb.h[7] = __float2bfloat16(fr[3].w);
    *reinterpret_cast<uint4*>(sm + loff + tid * 8)         = pa.u;
    *reinterpret_cast<uint4*>(sm + loff + (tid + 512) * 8) = pb.u;
}

#define SB0 __builtin_amdgcn_sched_barrier(0)
#define LGKM0 do { asm volatile("s_waitcnt lgkmcnt(0)" ::: "memory"); \
                   __builtin_amdgcn_sched_barrier(0); } while (0)
#define VMCNT(n) do { asm volatile("s_waitcnt vmcnt(" #n ")" ::: "memory"); \
                      __builtin_amdgcn_sched_barrier(0); } while (0)

template<int MH, bool RB>
__device__ __forceinline__ void phase_reads(
    const __hip_bfloat16* Ak, const __hip_bfloat16* Bk,
    int aoff, int boff, bf16x8 (&af)[4], bf16x8 (&bfk)[4])
{
    if constexpr (RB) {
        #pragma unroll
        for (int j = 0; j < 4; ++j)
            bfk[j] = *reinterpret_cast<const bf16x8*>(Bk + boff + j * 512);
    }
    #pragma unroll
    for (int i = 0; i < 4; ++i)
        af[i] = *reinterpret_cast<const bf16x8*>(Ak + aoff + (MH * 4 + i) * 512);
}

template<int MH>
__device__ __forceinline__ void phase_mfma16(
    const bf16x8 (&af)[4], const bf16x8 (&bfk)[4], f32x4 (&acc)[8][4])
{
    __builtin_amdgcn_s_setprio(1);
    #pragma unroll
    for (int i = 0; i < 4; ++i)
        #pragma unroll
        for (int j = 0; j < 4; ++j)
            acc[MH * 4 + i][j] = __builtin_amdgcn_mfma_f32_16x16x32_bf16(
                af[i], bfk[j], acc[MH * 4 + i][j], 0, 0, 0);
    __builtin_amdgcn_s_setprio(0);
}

template<typename OT, typename AT>
__device__ __forceinline__ void gemm_body256(
    const AT* __restrict__ A, const __hip_bfloat16* __restrict__ Wb,
    const float* __restrict__ bias, OT* __restrict__ out, float alpha,
    int m0, int n0, __hip_bfloat16* sm)
{
    constexpr bool A32 = std::is_same<AT, float>::value;

    const int tid  = threadIdx.x;
    const int wid  = tid >> 6;
    const int lane = tid & 63;
    const int quad = lane >> 4;
    const int l16  = lane & 15;
    const int wr   = wid >> 2, wc = wid & 3;   // 2 x 4 wave grid, 128x64 out each

    const int r0 = tid >> 2;
    const int s0 = (tid & 3) ^ ((tid >> 3) & 3);
    const int offA0 = (m0 + r0) * CH + s0 * 8;   // element offset (fp32 or bf16)
    const int offB0 = (n0 + r0) * CH + s0 * 8;

    const int cq   = quad ^ ((l16 >> 1) & 3);
    const int aoff = ((wr * 128 + l16) * 4 + cq) * 8;
    const int boff = ((wc * 64  + l16) * 4 + cq) * 8;

    f32x4 acc[8][4];
    #pragma unroll
    for (int i = 0; i < 8; ++i)
        #pragma unroll
        for (int j = 0; j < 4; ++j) acc[i][j] = zero4();

    float4 frA[4], frB[4];

    // ---- prologue: tile 0 -> buf 0
    if constexpr (A32) {
        stageA32_load(A, offA0,      frA);                 // klo  (loads 1-4)
        stageA32_load(A, offA0 + 32, frB);                 // khi  (5-8)
        stage_half(Wb, offB0,      sm, 32768,        tid); // Bklo (9-10)
        stage_half(Wb, offB0 + 32, sm, 32768 + 8192, tid); // Bkhi (11-12)
        VMCNT(8);  stageA32_write(frA, sm, 0,    tid);
        VMCNT(4);  stageA32_write(frB, sm, 8192, tid);
        VMCNT(2);                                          // Bklo landed
        LGKM0;                                             // writes visible
    } else {
        stage_half(A,  offA0,      sm, 0,             tid);
        stage_half(Wb, offB0,      sm, 32768,         tid);
        stage_half(A,  offA0 + 32, sm, 8192,          tid);
        stage_half(Wb, offB0 + 32, sm, 32768 + 8192,  tid);
        VMCNT(4);
    }
    __builtin_amdgcn_s_barrier();
    SB0;

    bf16x8 af[4], bfk[4];

    #pragma unroll 1
    for (int t = 0; t < 15; ++t) {
        const int cur = t & 1, nb = cur ^ 1;
        const int kn  = (t + 1) * 64;
        const __hip_bfloat16* As_ = sm + cur * 16384;
        const __hip_bfloat16* Bs_ = sm + 32768 + cur * 16384;

        // ---- p0: mfma (mh0, klo); stage klo(t+1) A (+B if A32)
        phase_reads<0, true>(As_, Bs_, aoff, boff, af, bfk);
        if constexpr (A32) {
            stageA32_load(A, offA0 + kn, frA);
            stage_half(Wb, offB0 + kn, sm, 32768 + nb * 16384, tid);
        } else {
            stage_half(A, offA0 + kn, sm, nb * 16384, tid);
        }
        SB0;
        __builtin_amdgcn_s_barrier();
        LGKM0;
        phase_mfma16<0>(af, bfk, acc);
        __builtin_amdgcn_s_barrier();

        // ---- p1: [A32: commit A-klo(t+1)]; mfma (mh1, klo)
        if constexpr (A32) {
            VMCNT(2);                                     // Bkhi(t)+Aklo(t+1) done
            stageA32_write(frA, sm, nb * 16384, tid);
        }
        phase_reads<1, false>(As_, Bs_, aoff, boff, af, bfk);
        if constexpr (!A32)
            stage_half(Wb, offB0 + kn, sm, 32768 + nb * 16384, tid);
        SB0;
        __builtin_amdgcn_s_barrier();
        LGKM0;
        phase_mfma16<1>(af, bfk, acc);
        if constexpr (!A32) VMCNT(4);
        __builtin_amdgcn_s_barrier();

        // ---- p2: mfma (mh0, khi); stage khi(t+1)
        phase_reads<0, true>(As_ + 8192, Bs_ + 8192, aoff, boff, af, bfk);
        if constexpr (A32) {
            stageA32_load(A, offA0 + kn + 32, frA);
            stage_half(Wb, offB0 + kn + 32, sm, 32768 + nb * 16384 + 8192, tid);
        } else {
            stage_half(A, offA0 + kn + 32, sm, nb * 16384 + 8192, tid);
        }
        SB0;
        __builtin_amdgcn_s_barrier();
        LGKM0;
        phase_mfma16<0>(af, bfk, acc);
        __builtin_amdgcn_s_barrier();

        // ---- p3: [A32: commit A-khi(t+1)]; mfma (mh1, khi)
        if constexpr (A32) {
            VMCNT(2);                                     // Bklo(t+1)+Akhi(t+1) done
            stageA32_write(frA, sm, nb * 16384 + 8192, tid);
        }
        phase_reads<1, false>(As_ + 8192, Bs_ + 8192, aoff, boff, af, bfk);
        if constexpr (!A32)
            stage_half(Wb, offB0 + kn + 32, sm, 32768 + nb * 16384 + 8192, tid);
        SB0;
        __builtin_amdgcn_s_barrier();
        LGKM0;
        phase_mfma16<1>(af, bfk, acc);
        if constexpr (!A32) VMCNT(4);
        __builtin_amdgcn_s_barrier();
    }

    // ---- peeled tail (t=15, cur=1): no staging
    {
        const __hip_bfloat16* As_ = sm + 16384;
        const __hip_bfloat16* Bs_ = sm + 32768 + 16384;

        phase_reads<0, true>(As_, Bs_, aoff, boff, af, bfk);
        SB0;
        __builtin_amdgcn_s_barrier();
        LGKM0;
        phase_mfma16<0>(af, bfk, acc);
        __builtin_amdgcn_s_barrier();

        if constexpr (A32) VMCNT(0);                      // drain Bkhi(15)
        phase_reads<1, false>(As_, Bs_, aoff, boff, af, bfk);
        SB0;
        __builtin_amdgcn_s_barrier();
        LGKM0;
        phase_mfma16<1>(af, bfk, acc);
        if constexpr (!A32) VMCNT(0);
        __builtin_amdgcn_s_barrier();

        phase_reads<0, true>(As_ + 8192, Bs_ + 8192, aoff, boff, af, bfk);
        SB0;
        __builtin_amdgcn_s_barrier();
        LGKM0;
        phase_mfma16<0>(af, bfk, acc);
        __builtin_amdgcn_s_barrier();

        phase_reads<1, false>(As_ + 8192, Bs_ + 8192, aoff, boff, af, bfk);
        SB0;
        __builtin_amdgcn_s_barrier();
        LGKM0;
        phase_mfma16<1>(af, bfk, acc);
    }

    // ---- epilogue
    #pragma unroll
    for (int j = 0; j < 4; ++j) {
        const int col = n0 + wc * 64 + j * 16 + l16;
        const float bv = bias[col];
        #pragma unroll
        for (int i = 0; i < 8; ++i) {
            #pragma unroll
            for (int r = 0; r < 4; ++r) {
                const int row = m0 + wr * 128 + i * 16 + quad * 4 + r;
                float v = alpha * (acc[i][j][r] + bv);
                if constexpr (std::is_same<OT, float>::value)
                    out[(size_t)row * CH + col] = v;
                else
                    out[(size_t)row * CH + col] = __float2bfloat16(v);
            }
        }
    }
}

__device__ __forceinline__ void gemm_tile256(int& m0, int& n0) {
    int bid = blockIdx.y * 4 + blockIdx.x;       // [0,256)
    int swz = (bid & 7) * 32 + (bid >> 3);
    m0 = (swz >> 2) * 256;
    n0 = (swz & 3) * 256;
}

__global__ __launch_bounds__(512, 2) void gemm_qk256(
    const float* __restrict__ A0, const __hip_bfloat16* __restrict__ W0,
    const float* __restrict__ b0, __hip_bfloat16* __restrict__ o0, float alpha0,
    const float* __restrict__ A1, const __hip_bfloat16* __restrict__ W1,
    const float* __restrict__ b1, __hip_bfloat16* __restrict__ o1)
{
    __shared__ alignas(16) __hip_bfloat16 sm[65536];   // 128 KiB
    int m0, n0; gemm_tile256(m0, n0);
    if (blockIdx.z == 0)
        gemm_body256<__hip_bfloat16, float>(A0, W0, b0, o0, alpha0, m0, n0, sm);
    else
        gemm_body256<__hip_bfloat16, float>(A1, W1, b1, o1, 1.0f, m0, n0, sm);
}

__global__ __launch_bounds__(512, 2) void gemm_v256(
    const float* __restrict__ A, const __hip_bfloat16* __restrict__ Wb,
    const float* __restrict__ bias, __hip_bfloat16* __restrict__ out)
{
    __shared__ alignas(16) __hip_bfloat16 sm[65536];
    int m0, n0; gemm_tile256(m0, n0);
    gemm_body256<__hip_bfloat16, float>(A, Wb, bias, out, 1.0f, m0, n0, sm);
}

__global__ __launch_bounds__(512, 2) void gemm_o256(
    const __hip_bfloat16* __restrict__ A, const __hip_bfloat16* __restrict__ Wb,
    const float* __restrict__ bias, float* __restrict__ out)
{
    __shared__ alignas(16) __hip_bfloat16 sm[65536];
    int m0, n0; gemm_tile256(m0, n0);
    gemm_body256<float, __hip_bfloat16>(A, Wb, bias, out, 1.0f, m0, n0, sm);
}

// ---------------------------------------------------------------------
// Attention (unchanged from R6): Q in regs, V issue-early/write-late,
// ps overlays ks, 3 blocks/CU.
// ---------------------------------------------------------------------
__global__ __launch_bounds__(256, 3) void attn_kernel(
    const __hip_bfloat16* __restrict__ qg,
    const __hip_bfloat16* __restrict__ kg,
    const __hip_bfloat16* __restrict__ vg,
    __hip_bfloat16* __restrict__ ctx)
{
    __shared__ alignas(16) char smem[53248];
    auto ks = reinterpret_cast<__hip_bfloat16(*)[72]>(smem);            // [192][72]
    auto vt = reinterpret_cast<__hip_bfloat16(*)[200]>(smem + 27648);   // [64][200]
    auto ps = reinterpret_cast<__hip_bfloat16(*)[200]>(smem);           // [64][200] (over ks)

    const int blk = xcd_swz(blockIdx.x, BATCH * NH * NBL);
    const int n = blk & (NBL - 1);
    const int h = (blk >> 7) & (NH - 1);
    const int b = blk >> 11;
    const int t0  = n * BLK;
    const int kst = t0 - 64;
    const int tid = threadIdx.x;
    const size_t baseBH = (size_t)b * SEQ * CH + (size_t)h * DH;

    const int wid = tid >> 6, lane = tid & 63, quad = lane >> 4, l16 = lane & 15;

    const __hip_bfloat16* qrow = qg + baseBH + (size_t)(t0 + wid * 16 + l16) * CH + quad * 8;
    bf16x8 aq0 = *reinterpret_cast<const bf16x8*>(qrow);
    bf16x8 aq1 = *reinterpret_cast<const bf16x8*>(qrow + 32);

    uint4 vreg[6];
    int vj[6], vseg[6];
    #pragma unroll
    for (int it = 0; it < 6; it++) {
        int c = tid + it * 256;
        vj[it] = c % WIN; vseg[it] = c / WIN;
        int tr = kst + vj[it]; tr = tr < 0 ? 0 : (tr >= SEQ ? SEQ - 1 : tr);
        vreg[it] = *reinterpret_cast<const uint4*>(vg + baseBH + (size_t)tr * CH + vseg[it] * 8);
    }

    #pragma unroll
    for (int it = 0; it < 6; it++) {
        int c = tid + it * 256;
        int row = c >> 3, seg = c & 7;
        int tr = kst + row; tr = tr < 0 ? 0 : (tr >= SEQ ? SEQ - 1 : tr);
        *reinterpret_cast<uint4*>(&ks[row][seg * 8]) =
            *reinterpret_cast<const uint4*>(kg + baseBH + (size_t)tr * CH + seg * 8);
    }
    __syncthreads();

    f32x4 sc[12];
    #pragma unroll
    for (int j = 0; j < 12; j++) sc[j] = zero4();
    #pragma unroll
    for (int j = 0; j < 12; j++) {
        bf16x8 bk0 = *reinterpret_cast<const bf16x8*>(&ks[j * 16 + l16][quad * 8]);
        sc[j] = __builtin_amdgcn_mfma_f32_16x16x32_bf16(aq0, bk0, sc[j], 0, 0, 0);
        bf16x8 bk1 = *reinterpret_cast<const bf16x8*>(&ks[j * 16 + l16][32 + quad * 8]);
        sc[j] = __builtin_amdgcn_mfma_f32_16x16x32_bf16(aq1, bk1, sc[j], 0, 0, 0);
    }
    __syncthreads();

    #pragma unroll
    for (int it = 0; it < 6; it++) {
        Pack8 p; p.u = vreg[it];
        #pragma unroll
        for (int e = 0; e < 8; e++) vt[vseg[it] * 8 + e][vj[it]] = p.h[e];
    }

    #pragma unroll
    for (int r = 0; r < 4; r++) {
        float s[12];
        float mx = -3.0e38f;
        #pragma unroll
        for (int j = 0; j < 12; j++) {
            int col = j * 16 + l16;
            int tr = kst + col;
            bool valid = (tr >= 0) && (tr < SEQ);
            s[j] = valid ? sc[j][r] : -3.0e38f;
            mx = fmaxf(mx, s[j]);
        }
        #pragma unroll
        for (int o = 1; o < 16; o <<= 1) mx = fmaxf(mx, __shfl_xor(mx, o, 64));
        float sum = 0.f;
        #pragma unroll
        for (int j = 0; j < 12; j++) {
            float e = __expf(s[j] - mx);
            s[j] = e;
            sum += e;
        }
        #pragma unroll
        for (int o = 1; o < 16; o <<= 1) sum += __shfl_xor(sum, o, 64);
        const float inv = 1.f / sum;
        const int row = wid * 16 + quad * 4 + r;
        #pragma unroll
        for (int j = 0; j < 12; j++)
            ps[row][j * 16 + l16] = __float2bfloat16(s[j] * inv);
    }
    __syncthreads();

    f32x4 oa[4];
    #pragma unroll
    for (int j = 0; j < 4; j++) oa[j] = zero4();
    #pragma unroll
    for (int kk = 0; kk < 6; kk++) {
        bf16x8 ap = *reinterpret_cast<const bf16x8*>(&ps[wid * 16 + l16][kk * 32 + quad * 8]);
        #pragma unroll
        for (int j = 0; j < 4; j++) {
            bf16x8 bv = *reinterpret_cast<const bf16x8*>(&vt[j * 16 + l16][kk * 32 + quad * 8]);
            oa[j] = __builtin_amdgcn_mfma_f32_16x16x32_bf16(ap, bv, oa[j], 0, 0, 0);
        }
    }
    #pragma unroll
    for (int j = 0; j < 4; j++) {
        const int d = j * 16 + l16;
        #pragma unroll
        for (int r = 0; r < 4; r++) {
            const int i = wid * 16 + quad * 4 + r;
            ctx[baseBH + (size_t)(t0 + i) * CH + d] = __float2bfloat16(oa[j][r]);
        }
    }
}

extern "C" void kernel_launch(void* const* d_in, const int* in_sizes, int n_in,
                              void* d_out, int out_size, void* d_ws, size_t ws_size,
                              hipStream_t stream)
{
    const float* query = (const float*)d_in[0];
    const float* key_i = (const float*)d_in[1];
    const float* value = (const float*)d_in[2];
    const float* Wq = (const float*)d_in[3];
    const float* bq = (const float*)d_in[4];
    const float* Wk = (const float*)d_in[5];
    const float* bk = (const float*)d_in[6];
    const float* Wv = (const float*)d_in[7];
    const float* bv = (const float*)d_in[8];
    const float* Wo = (const float*)d_in[9];
    const float* bo = (const float*)d_in[10];
    float* out = (float*)d_out;

    const size_t NELEM = (size_t)MR * CH;   // 16,777,216
    const size_t WELEM = (size_t)CH * CH;   // 1,048,576

    __hip_bfloat16* S0 = (__hip_bfloat16*)d_ws;
    __hip_bfloat16* S1 = S0 + NELEM;
    __hip_bfloat16* S2 = S1 + NELEM;
    __hip_bfloat16* S3 = S2 + NELEM;
    __hip_bfloat16* wqb = S3;
    __hip_bfloat16* wkb = S3 + WELEM;
    __hip_bfloat16* wvb = S3 + 2 * WELEM;
    __hip_bfloat16* wob = S3 + 3 * WELEM;

    __hip_bfloat16* vb = (__hip_bfloat16*)d_out;   // scratch until out-GEMM
    __hip_bfloat16* qb = S1;
    __hip_bfloat16* kb = S2;
    __hip_bfloat16* cb = S0;

    const int NW8B = (int)((WELEM / 8) / 256);   // 512

    pack_w<<<4 * NW8B, 256, 0, stream>>>(Wq, Wk, Wv, Wo, wqb, wkb, wvb, wob);

    dim3 ggrid(CH / 256, MR / 256);         // (4, 64)
    dim3 qkgrid(CH / 256, MR / 256, 2);     // 512 blocks

    gemm_qk256<<<qkgrid, 512, 0, stream>>>(query, wqb, bq, qb, 0.125f,
                                           key_i, wkb, bk, kb);
    gemm_v256<<<ggrid, 512, 0, stream>>>(value, wvb, bv, vb);

    attn_kernel<<<BATCH * NH * NBL, 256, 0, stream>>>(qb, kb, vb, cb);

    gemm_o256<<<ggrid, 512, 0, stream>>>(cb, wob, bo, out);
}